// Round 1
// baseline (4944.674 us; speedup 1.0000x reference)
//
#include <hip/hip_runtime.h>
#include <hip/hip_bf16.h>

#define B 64
#define T 8192
#define D 16
#define H 128
#define F 17      // D + 1 features (particles + weight channel)
#define KPAD 160  // 128 (h) + 17 (x) + 15 pad
#define NK2 80    // KPAD/2 fp16 pairs
#define NTHREADS 512

typedef _Float16 half_t;
typedef _Float16 half2_t __attribute__((ext_vector_type(2)));

__device__ __forceinline__ float dot2acc(half2_t a, half2_t b, float c) {
#if __has_builtin(__builtin_amdgcn_fdot2)
  return __builtin_amdgcn_fdot2(a, b, c, false);
#else
  return c + (float)a.x * (float)b.x + (float)a.y * (float)b.y;
#endif
}

__device__ __forceinline__ float fast_rcp(float x) {
#if __has_builtin(__builtin_amdgcn_rcpf)
  return __builtin_amdgcn_rcpf(x);
#else
  return 1.0f / x;
#endif
}

// Unrolled dot over uint4 blocks [LO, HI) of the LDS h' vector.
#define DOT_RANGE(LO, HI)                                                   \
    _Pragma("unroll")                                                       \
    for (int m4 = (LO); m4 < (HI); ++m4) {                                  \
      uint4 u = hv4[m4];                                                    \
      acc = dot2acc(__builtin_bit_cast(half2_t, u.x), wv[4*m4+0], acc);     \
      acc = dot2acc(__builtin_bit_cast(half2_t, u.y), wv[4*m4+1], acc);     \
      acc = dot2acc(__builtin_bit_cast(half2_t, u.z), wv[4*m4+2], acc);     \
      acc = dot2acc(__builtin_bit_cast(half2_t, u.w), wv[4*m4+3], acc);     \
    }

// One GRU timestep. XV is the register holding x_{tt+1} (staged to LDS now);
// we then issue the load of x_{tt+3} into it (2-step prefetch pipeline).
#define STEP(tt, XV)                                                        \
  do {                                                                      \
    float acc = bias;                                                       \
    const uint4* hv4 = (const uint4*)h2;                                    \
    if (g < 2)       { DOT_RANGE(0, 19) }   /* r,z fused: pairs 0..75   */  \
    else if (g == 2) { DOT_RANGE(0, 16) }   /* hn: h-part only, 0..63   */  \
    else             { DOT_RANGE(16, 19) }  /* inn: x-part only, 64..75 */  \
    sg[tid] = acc;                                                          \
    __syncthreads();                                                        \
    if (tid < H) {                                                          \
      float s_r  = sg[tid],       s_z  = sg[128 + tid];                     \
      float s_hn = sg[256 + tid], s_in = sg[384 + tid];                     \
      float r = fast_rcp(1.0f + __expf(-s_r));                              \
      float z = fast_rcp(1.0f + __expf(-s_z));                              \
      float pre = fmaf(r, s_hn, s_in);                                      \
      pre = fminf(fmaxf(pre, -15.0f), 15.0f);                               \
      float e = __expf(-2.0f * pre);                                        \
      float n = (1.0f - e) * fast_rcp(1.0f + e);                            \
      hreg = fmaf(z, hreg - n, n);   /* (1-z)*n + z*h */                    \
      hh[tid] = (half_t)hreg;                                               \
    }                                                                       \
    if (isx) {                                                              \
      hh[H + xi] = (half_t)(XV);                                            \
      XV = xload((tt) + 3 < T ? (tt) + 3 : T - 1);                          \
    }                                                                       \
    __syncthreads();                                                        \
  } while (0)

__global__ __launch_bounds__(NTHREADS)
void policy_gru_kernel(const float* __restrict__ particles,
                       const float* __restrict__ weights,
                       const float* __restrict__ Wi, const float* __restrict__ Wh,
                       const float* __restrict__ bh,
                       const float* __restrict__ W1, const float* __restrict__ b1,
                       const float* __restrict__ W2, const float* __restrict__ b2,
                       const float* __restrict__ W3, const float* __restrict__ b3,
                       const float* __restrict__ log_std,
                       float* __restrict__ out)
{
  // h' = [h(128) | x_t(17) | pad(15)] as fp16 pairs; sg = pre-activations.
  __shared__ __align__(16) half2_t h2[NK2];
  __shared__ float sg[NTHREADS];
  __shared__ float red[8];

  const int tid = threadIdx.x;
  const int b   = blockIdx.x;
  const int g   = tid >> 7;      // 0:r  1:z  2:hn  3:inn
  const int j   = tid & 127;
  const int c   = (g == 0) ? j : (g == 1) ? 128 + j : 256 + j;

  // ---- pack this thread's weight column as fp16 pairs over KPAD ----
  // col layout: k<128 -> Wh[k][c] (g<3); k in [128,145) -> Wi[k-128][c]
  // (g in {0,1,3}); else 0.
  half2_t wv[NK2];
  float bias = (g < 3) ? bh[c] : 0.0f;
  #pragma unroll
  for (int m = 0; m < NK2; ++m) {
    const int k0 = 2 * m, k1 = 2 * m + 1;
    float v0 = 0.0f, v1 = 0.0f;
    if (k1 < 128) {
      if (g < 3) { v0 = Wh[k0 * 384 + c]; v1 = Wh[k1 * 384 + c]; }
    } else {  // k0 >= 128 (128 is even, pairs never straddle)
      if (g != 2) {
        const int i0 = k0 - 128, i1 = k1 - 128;
        if (i0 < F) v0 = Wi[i0 * 384 + c];
        if (i1 < F) v1 = Wi[i1 * 384 + c];
      }
    }
    wv[m] = half2_t{(half_t)v0, (half_t)v1};
  }

  // ---- x prefetch lanes: wave 4, lanes 0..16 ----
  const int xi = tid - 256;
  const bool isx = (xi >= 0 && xi < F);
  auto xload = [&](int t) -> float {
    if (!isx) return 0.0f;
    if (xi < D) return particles[((size_t)b * T + t) * D + xi];
    return weights[(size_t)b * T + t];
  };

  half_t* hh = (half_t*)h2;

  // init: zero h' (incl. pad), then stage x_0 and prime the prefetch regs
  if (tid < NK2) h2[tid] = half2_t{(half_t)0.0f, (half_t)0.0f};
  float hreg = 0.0f;  // persistent h_old[j] for tid < 128
  __syncthreads();
  if (isx) hh[H + xi] = (half_t)xload(0);
  float xA = xload(1);
  float xB = xload(2);
  __syncthreads();

  // ---- the sequential scan ----
  for (int t = 0; t < T; t += 2) {
    STEP(t, xA);
    STEP(t + 1, xB);
  }

  // ---- MLP head (fp32) ----
  if (tid < H) sg[tid] = hreg;  // final hidden state
  __syncthreads();

  float a1 = 0.0f;
  if (tid < 256) {
    a1 = b1[tid];
    #pragma unroll 4
    for (int k = 0; k < H; ++k) a1 = fmaf(sg[k], W1[k * 256 + tid], a1);
    a1 = fmaxf(a1, 0.0f);
    sg[256 + tid] = a1;  // disjoint from sg[0..127] being read
  }
  __syncthreads();

  float a2 = 0.0f;
  if (tid < 256) {
    a2 = b2[tid];
    #pragma unroll 4
    for (int k = 0; k < 256; ++k) a2 = fmaf(sg[256 + k], W2[k * 256 + tid], a2);
    a2 = fmaxf(a2, 0.0f);
    a2 *= W3[tid];  // W3 is [256,1]
  }
  // wave reduction (64-wide), then cross-wave via LDS
  #pragma unroll
  for (int off = 32; off > 0; off >>= 1) a2 += __shfl_down(a2, off, 64);
  if (tid < 256 && (tid & 63) == 0) red[tid >> 6] = a2;
  __syncthreads();
  if (tid == 0) {
    out[b] = red[0] + red[1] + red[2] + red[3] + b3[0];
    if (b == 0) out[B] = log_std[0];  // second output, flat index 64
  }
}

extern "C" void kernel_launch(void* const* d_in, const int* in_sizes, int n_in,
                              void* d_out, int out_size, void* d_ws, size_t ws_size,
                              hipStream_t stream) {
  const float* particles = (const float*)d_in[0];
  const float* weights   = (const float*)d_in[1];
  const float* Wi      = (const float*)d_in[2];
  const float* Wh      = (const float*)d_in[3];
  const float* bh      = (const float*)d_in[4];
  const float* W1      = (const float*)d_in[5];
  const float* b1      = (const float*)d_in[6];
  const float* W2      = (const float*)d_in[7];
  const float* b2      = (const float*)d_in[8];
  const float* W3      = (const float*)d_in[9];
  const float* b3      = (const float*)d_in[10];
  const float* log_std = (const float*)d_in[11];

  policy_gru_kernel<<<dim3(B), dim3(NTHREADS), 0, stream>>>(
      particles, weights, Wi, Wh, bh, W1, b1, W2, b2, W3, b3, log_std,
      (float*)d_out);
}

// Round 2
// 3178.767 us; speedup vs baseline: 1.5555x; 1.5555x over previous
//
#include <hip/hip_runtime.h>
#include <hip/hip_bf16.h>

#define B 64
#define T 8192
#define D 16
#define H 128
#define F 17       // D + 1 features (particles + weight channel)
#define NTHREADS 512

typedef _Float16 half_t;
typedef _Float16 f16x8 __attribute__((ext_vector_type(8)));
typedef float f32x4 __attribute__((ext_vector_type(4)));

#define MFMA(a, b, c) __builtin_amdgcn_mfma_f32_16x16x32_f16((a), (b), (c), 0, 0, 0)

__device__ __forceinline__ float fast_rcp(float x) {
#if __has_builtin(__builtin_amdgcn_rcpf)
  return __builtin_amdgcn_rcpf(x);
#else
  return 1.0f / x;
#endif
}

// One GRU timestep. Reads h'=[h_t | x_t | 0pad] (160 halfs) from RBUF,
// computes h_{t+1} fully in-lane via MFMA broadcast-row trick, writes
// h_{t+1} + x_{t+1} into WBUF. ONE barrier per step (double-buffered h').
#define GSTEP(RBUF, WBUF, tt, XV)                                          \
  do {                                                                     \
    const f16x8* hv8 = (const f16x8*)(RBUF);                               \
    f16x8 a0 = hv8[g16], a1 = hv8[4 + g16], a2 = hv8[8 + g16],             \
          a3 = hv8[12 + g16], a4 = hv8[16 + g16];                          \
    f32x4 ar = {b_r, b_r, b_r, b_r}, az = {b_z, b_z, b_z, b_z},            \
          an = {b_n, b_n, b_n, b_n}, ai = {0.f, 0.f, 0.f, 0.f};            \
    ar = MFMA(a0, wr0, ar); az = MFMA(a0, wz0, az); an = MFMA(a0, wn0, an);\
    ar = MFMA(a1, wr1, ar); az = MFMA(a1, wz1, az); an = MFMA(a1, wn1, an);\
    ar = MFMA(a2, wr2, ar); az = MFMA(a2, wz2, az); an = MFMA(a2, wn2, an);\
    ar = MFMA(a3, wr3, ar); az = MFMA(a3, wz3, az); an = MFMA(a3, wn3, an);\
    ar = MFMA(a4, wr4, ar); az = MFMA(a4, wz4, az); ai = MFMA(a4, wi4, ai);\
    float rr = fast_rcp(1.0f + __expf(-ar[0]));                            \
    float zz = fast_rcp(1.0f + __expf(-az[0]));                            \
    float pre = fmaf(rr, an[0], ai[0]);                                    \
    pre = fminf(fmaxf(pre, -15.0f), 15.0f);                                \
    float e2 = __expf(-2.0f * pre);                                        \
    float nn = (1.0f - e2) * fast_rcp(1.0f + e2);                          \
    hreg = fmaf(zz, hreg - nn, nn); /* (1-z)*n + z*h */                    \
    if (g16 == 0) (WBUF)[jj] = (half_t)hreg;                               \
    if (isx) { (WBUF)[H + tid] = (half_t)(XV);                             \
               XV = xload((tt) + 3 < T ? (tt) + 3 : T - 1); }              \
    __syncthreads();                                                       \
  } while (0)

__global__ __launch_bounds__(NTHREADS)
void policy_gru_kernel(const float* __restrict__ particles,
                       const float* __restrict__ weights,
                       const float* __restrict__ Wi, const float* __restrict__ Wh,
                       const float* __restrict__ bh,
                       const float* __restrict__ W1, const float* __restrict__ b1,
                       const float* __restrict__ W2, const float* __restrict__ b2,
                       const float* __restrict__ W3, const float* __restrict__ b3,
                       const float* __restrict__ log_std,
                       float* __restrict__ out)
{
  // h' double buffer: [h(128) | x(17) | pad(15)] fp16
  __shared__ __align__(16) half_t hbuf[2][160];
  __shared__ float sg[NTHREADS];
  __shared__ float red[8];

  const int tid = threadIdx.x;
  const int b   = blockIdx.x;
  const int l   = tid & 63;
  const int w   = tid >> 6;       // wave 0..7
  const int g16 = l >> 4;         // k-block group 0..3 within wave
  const int jn  = l & 15;         // col within 16-tile
  const int jj  = w * 16 + jn;    // hidden unit 0..127 owned by this lane

  // ---- pack weight B-fragments (persistent in VGPRs) ----
  // tile g: gate (0:r 1:z 2:hn 3:inn); K-step s: k = s*32 + g16*8 + r.
  // B[k][n]: n = jj. r/z fuse Wh (k<128) and Wi (128<=k<145); hn: Wh only;
  // inn: Wi only (nonzero solely in k-step 4).
  auto wload = [&](int gate, int s) -> f16x8 {
    f16x8 v;
    #pragma unroll
    for (int r = 0; r < 8; ++r) {
      const int k = s * 32 + g16 * 8 + r;
      float f = 0.0f;
      const int col = (gate == 0) ? jj : (gate == 1) ? 128 + jj : 256 + jj;
      if (gate <= 1) {
        if (k < 128) f = Wh[k * 384 + col];
        else if (k < 128 + F) f = Wi[(k - 128) * 384 + col];
      } else if (gate == 2) {
        if (k < 128) f = Wh[k * 384 + col];
      } else {
        if (k >= 128 && k < 128 + F) f = Wi[(k - 128) * 384 + col];
      }
      v[r] = (half_t)f;
    }
    return v;
  };
  const f16x8 wr0 = wload(0, 0), wr1 = wload(0, 1), wr2 = wload(0, 2),
              wr3 = wload(0, 3), wr4 = wload(0, 4);
  const f16x8 wz0 = wload(1, 0), wz1 = wload(1, 1), wz2 = wload(1, 2),
              wz3 = wload(1, 3), wz4 = wload(1, 4);
  const f16x8 wn0 = wload(2, 0), wn1 = wload(2, 1), wn2 = wload(2, 2),
              wn3 = wload(2, 3);
  const f16x8 wi4 = wload(3, 4);
  const float b_r = bh[jj], b_z = bh[128 + jj], b_n = bh[256 + jj];

  // ---- x prefetch: threads 0..16 (lanes of wave 0) ----
  const bool isx = tid < F;
  auto xload = [&](int t) -> float {
    if (!isx) return 0.0f;
    if (tid < D) return particles[((size_t)b * T + t) * D + tid];
    return weights[(size_t)b * T + t];
  };

  // init: zero both h' buffers (incl. pad), stage x_0, prime prefetch
  if (tid < 160) { hbuf[0][tid] = (half_t)0.f; hbuf[1][tid] = (half_t)0.f; }
  float hreg = 0.0f;  // h_t[jj], replicated across the 4 g16 lane groups
  __syncthreads();
  if (isx) hbuf[0][H + tid] = (half_t)xload(0);
  float xA = xload(1);
  float xB = xload(2);
  __syncthreads();

  // ---- sequential scan, 1 barrier per step ----
  for (int t = 0; t < T; t += 2) {
    GSTEP(hbuf[0], hbuf[1], t, xA);
    GSTEP(hbuf[1], hbuf[0], t + 1, xB);
  }

  // ---- MLP head (fp32) ----
  if (g16 == 0) sg[jj] = hreg;  // final hidden state as f32
  __syncthreads();

  float a1 = 0.0f;
  if (tid < 256) {
    a1 = b1[tid];
    #pragma unroll 4
    for (int k = 0; k < H; ++k) a1 = fmaf(sg[k], W1[k * 256 + tid], a1);
    a1 = fmaxf(a1, 0.0f);
    sg[256 + tid] = a1;  // disjoint from sg[0..127]
  }
  __syncthreads();

  float a2 = 0.0f;
  if (tid < 256) {
    a2 = b2[tid];
    #pragma unroll 4
    for (int k = 0; k < 256; ++k) a2 = fmaf(sg[256 + k], W2[k * 256 + tid], a2);
    a2 = fmaxf(a2, 0.0f);
    a2 *= W3[tid];  // W3 is [256,1]
  }
  #pragma unroll
  for (int off = 32; off > 0; off >>= 1) a2 += __shfl_down(a2, off, 64);
  if (tid < 256 && (tid & 63) == 0) red[tid >> 6] = a2;
  __syncthreads();
  if (tid == 0) {
    out[b] = red[0] + red[1] + red[2] + red[3] + b3[0];
    if (b == 0) out[B] = log_std[0];  // second output, flat index 64
  }
}

extern "C" void kernel_launch(void* const* d_in, const int* in_sizes, int n_in,
                              void* d_out, int out_size, void* d_ws, size_t ws_size,
                              hipStream_t stream) {
  const float* particles = (const float*)d_in[0];
  const float* weights   = (const float*)d_in[1];
  const float* Wi      = (const float*)d_in[2];
  const float* Wh      = (const float*)d_in[3];
  const float* bh      = (const float*)d_in[4];
  const float* W1      = (const float*)d_in[5];
  const float* b1      = (const float*)d_in[6];
  const float* W2      = (const float*)d_in[7];
  const float* b2      = (const float*)d_in[8];
  const float* W3      = (const float*)d_in[9];
  const float* b3      = (const float*)d_in[10];
  const float* log_std = (const float*)d_in[11];

  policy_gru_kernel<<<dim3(B), dim3(NTHREADS), 0, stream>>>(
      particles, weights, Wi, Wh, bh, W1, b1, W2, b2, W3, b3, log_std,
      (float*)d_out);
}